// Round 4
// baseline (49.862 us; speedup 1.0000x reference)
//
#include <hip/hip_runtime.h>
#include <math.h>

#define M_GT 128
#define NLEV 5
#define KCAND 135   // 5 levels * 27
#define TOPK_LOC 9
#define GX 186      // focal blocks per sample: 96+48+24+12+6 (256 anchors each, level-pure)

__device__ __forceinline__ float waveReduceSumF(float v) {
    #pragma unroll
    for (int off = 32; off > 0; off >>= 1)
        v += __shfl_xor(v, off, 64);
    return v;
}

// One wave per (b, m) pair; 4 pairs per 256-thread block.
// Writes per (b, level, m): float4 {gs, ge, thresh, window_lo(bitcast int)}.
// Also zeroes the done-counter used by the focal kernel's last-block finalize.
__global__ __launch_bounds__(256) void atss_summary_kernel(
    const float* __restrict__ ann,   // [B, 128, 3]
    const float* __restrict__ a0,
    const float* __restrict__ a1,
    const float* __restrict__ a2,
    const float* __restrict__ a3,
    const float* __restrict__ a4,
    float4* __restrict__ rec,        // [B][NLEV][M_GT]
    unsigned int* __restrict__ cnt)
{
    if (blockIdx.x == 0 && threadIdx.x == 0) *cnt = 0u;

    const int Llev[NLEV] = {8192, 4096, 2048, 1024, 512};
    const float* aptr[NLEV] = {a0, a1, a2, a3, a4};

    int wid  = threadIdx.x >> 6;
    int lane = threadIdx.x & 63;
    int pair = blockIdx.x*4 + wid;
    int b = pair >> 7, m = pair & 127;
    const float* g = ann + ((size_t)b*M_GT + m)*3;
    float gs = g[0], ge = g[1];
    float gc = (gs + ge)*0.5f;
    float glen = ge - gs;

    // Per level: contiguous window of the 9 nearest locations.
    // Centers (j+0.5)*s are exact f32 (s = power of two); same-side distances
    // strictly ordered; cross-side tie -> lower index (matches lax.top_k).
    int lo_arr[NLEV];
    #pragma unroll
    for (int l = 0; l < NLEV; ++l) {
        int L = Llev[l];
        float s = 65536.0f / (float)L;
        int j0 = (int)floorf(gc / s);
        if (j0 < 0) j0 = 0;
        if (j0 > L-1) j0 = L-1;
        int best = j0;
        float bd = fabsf(((float)j0 + 0.5f)*s - gc);
        if (j0 > 0) {
            float d = fabsf(((float)j0 - 0.5f)*s - gc);
            if (d <= bd) { best = j0-1; bd = d; }
        }
        if (j0+1 < L) {
            float d = fabsf(((float)j0 + 1.5f)*s - gc);
            if (d < bd)  { best = j0+1; bd = d; }
        }
        int lo = best, hi = best+1;
        #pragma unroll
        for (int t = 1; t < TOPK_LOC; ++t) {
            float dl = (lo > 0) ? fabsf(((float)(lo-1) + 0.5f)*s - gc) : 3.4e38f;
            float dr = (hi < L) ? fabsf(((float)hi    + 0.5f)*s - gc) : 3.4e38f;
            if (dl <= dr) --lo; else ++hi;          // tie -> left (lower index)
        }
        lo_arr[l] = lo;
    }

    // 135 candidate IoUs spread over lanes -> mean + unbiased std -> thresh
    float iouv[3];
    int valid[3];
    float sum = 0.f;
    #pragma unroll
    for (int it = 0; it < 3; ++it) {
        int c = lane + it*64;
        valid[it] = 0; iouv[it] = 0.f;
        if (c < KCAND) {
            int lev = c / 27;
            int w   = c % 27;
            int loc = lo_arr[lev] + w/3;
            int sc  = w % 3;
            int lidx = loc*3 + sc;
            const float* ap = aptr[lev] + (size_t)lidx*2;
            float as_ = ap[0], ae_ = ap[1];
            float iw = fminf(ae_, ge) - fmaxf(as_, gs);
            iw = fmaxf(iw, 0.f);
            float ua = (ae_ - as_) + glen - iw;
            ua = fmaxf(ua, 1e-8f);
            float iou = iw / ua;
            iouv[it] = iou;
            valid[it] = 1;
            sum += iou;
        }
    }
    sum = waveReduceSumF(sum);
    float mean = sum / (float)KCAND;
    float s2 = 0.f;
    #pragma unroll
    for (int it = 0; it < 3; ++it)
        if (valid[it]) { float d = iouv[it] - mean; s2 += d*d; }
    s2 = waveReduceSumF(s2);
    float thresh = mean + sqrtf(s2 / (float)(KCAND - 1));  // ddof=1

    // static-index select (avoid runtime-indexed array -> scratch)
    if (lane < NLEV) {
        int lo_sel = (lane == 0) ? lo_arr[0] :
                     (lane == 1) ? lo_arr[1] :
                     (lane == 2) ? lo_arr[2] :
                     (lane == 3) ? lo_arr[3] : lo_arr[4];
        rec[((size_t)b*NLEV + lane)*M_GT + m] =
            make_float4(gs, ge, thresh, __int_as_float(lo_sel));
    }
}

// One block = 256 consecutive anchors of one level. Derives pos on the fly
// from the summary records (bit-identical IoU sequence), sums focal loss,
// writes a float2 partial, and the LAST block to finish does the final
// deterministic reduction (device-scope fence + counter).
__global__ __launch_bounds__(256) void focal_kernel(
    const float* __restrict__ cls,   // [B, A, C]
    const float4* __restrict__ rec,  // [B][NLEV][M_GT]
    const int* __restrict__ cidp,
    const float* __restrict__ a0,
    const float* __restrict__ a1,
    const float* __restrict__ a2,
    const float* __restrict__ a3,
    const float* __restrict__ a4,
    float2* __restrict__ parts,      // [B*GX] {sum, count}
    unsigned int* __restrict__ cnt,
    float* __restrict__ out,
    int A, int C, int B)
{
    const float* aptr[NLEV] = {a0, a1, a2, a3, a4};
    const int gbase[NLEV] = {0, 24576, 36864, 43008, 46080};

    int xb = blockIdx.x;
    int b  = blockIdx.y;
    int lev, lstart;
    if      (xb <  96) { lev = 0; lstart = 0;   }
    else if (xb < 144) { lev = 1; lstart = 96;  }
    else if (xb < 168) { lev = 2; lstart = 144; }
    else if (xb < 180) { lev = 3; lstart = 168; }
    else               { lev = 4; lstart = 180; }
    int a0l = (xb - lstart) * 256;   // level-local anchor offset
    int tid = threadIdx.x;
    int cid = *cidp;

    __shared__ float4 srec[M_GT];
    __shared__ int    slist[M_GT];
    __shared__ int    scount;
    if (tid == 0) scount = 0;
    __syncthreads();
    if (tid < M_GT) {
        float4 r = rec[((size_t)b*NLEV + lev)*M_GT + tid];
        srec[tid] = r;
        int lo = __float_as_int(r.w);
        int locLo = a0l / 3;
        int locHi = (a0l + 255) / 3;
        if (lo <= locHi && lo + TOPK_LOC - 1 >= locLo) {
            int slot = atomicAdd(&scount, 1);
            slist[slot] = tid;
        }
    }
    __syncthreads();
    int nlist = scount;

    // positivity for my anchor
    int lidx = a0l + tid;
    const float2 aa = ((const float2*)aptr[lev])[lidx];
    float as_ = aa.x, ae_ = aa.y;
    float cx  = (as_ + ae_) * 0.5f;
    int   loc = lidx / 3;
    int myp = 0;
    for (int i = 0; i < nlist; ++i) {
        float4 r = srec[slist[i]];
        int lo = __float_as_int(r.w);
        if (loc >= lo && loc < lo + TOPK_LOC) {
            float gs = r.x, ge = r.y;
            float glen = ge - gs;
            float iw = fminf(ae_, ge) - fmaxf(as_, gs);
            iw = fmaxf(iw, 0.f);
            float ua = (ae_ - as_) + glen - iw;
            ua = fmaxf(ua, 1e-8f);
            float iou = iw / ua;
            if (iou >= r.z && fminf(cx - gs, ge - cx) > 0.01f) { myp = 1; break; }
        }
    }

    // focal sum over channels
    int ga = gbase[lev] + lidx;      // global anchor index
    const float* p = cls + ((size_t)b*A + ga)*C;
    float local = 0.f;
    if (C == 8) {
        const float4* p4 = (const float4*)p;
        float4 u = p4[0], v = p4[1];
        float x8[8] = {u.x, u.y, u.z, u.w, v.x, v.y, v.z, v.w};
        #pragma unroll
        for (int c = 0; c < 8; ++c) {
            float x = fminf(fmaxf(x8[c], 1e-4f), 0.9999f);
            bool one = (myp != 0) && (c == cid);
            if (one) { float q = 1.f - x; local += 0.25f * q*q * (-__logf(x)); }
            else     {                     local += 0.75f * x*x * (-__logf(1.f - x)); }
        }
    } else {
        for (int c = 0; c < C; ++c) {
            float x = fminf(fmaxf(p[c], 1e-4f), 0.9999f);
            bool one = (myp != 0) && (c == cid);
            if (one) { float q = 1.f - x; local += 0.25f * q*q * (-__logf(x)); }
            else     {                     local += 0.75f * x*x * (-__logf(1.f - x)); }
        }
    }

    // wave reduce, then cross-wave via LDS (4 waves)
    local = waveReduceSumF(local);
    float cf = waveReduceSumF((float)myp);
    __shared__ float sred[4];
    __shared__ float cred[4];
    __shared__ bool  slast;
    int wid = tid >> 6;
    if ((tid & 63) == 0) { sred[wid] = local; cred[wid] = cf; }
    __syncthreads();
    if (tid == 0) {
        float s = sred[0] + sred[1] + sred[2] + sred[3];
        float c = cred[0] + cred[1] + cred[2] + cred[3];
        parts[(size_t)b*GX + xb] = make_float2(s, c);
        __threadfence();                       // publish partial (device scope)
        unsigned int old = atomicAdd(cnt, 1u); // arrival ticket
        slast = (old == (unsigned int)(GX*B - 1));
    }
    __syncthreads();

    if (slast) {
        __threadfence();                       // acquire all partials
        if (tid < 64) {
            float total = 0.f;
            for (int bb = 0; bb < B; ++bb) {
                float s = 0.f, c = 0.f;
                for (int g = tid; g < GX; g += 64) {
                    const volatile float* pp =
                        (const volatile float*)&parts[(size_t)bb*GX + g];
                    s += pp[0];
                    c += pp[1];
                }
                s = waveReduceSumF(s);
                c = waveReduceSumF(c);
                total += s / fmaxf(c, 1.0f);
            }
            if (tid == 0) {
                out[0] = total / (float)B;
                *cnt = 0;                      // self-clean (also re-zeroed by k1)
            }
        }
    }
}

extern "C" void kernel_launch(void* const* d_in, const int* in_sizes, int n_in,
                              void* d_out, int out_size, void* d_ws, size_t ws_size,
                              hipStream_t stream)
{
    const float* cls = (const float*)d_in[0];
    const float* ann = (const float*)d_in[1];
    const int* cid;
    const float *a0, *a1, *a2, *a3, *a4;
    int ai;
    if (in_sizes[2] == 1) { cid = (const int*)d_in[2]; ai = 3; }
    else                  { cid = (const int*)d_in[7]; ai = 2; }
    a0 = (const float*)d_in[ai+0];
    a1 = (const float*)d_in[ai+1];
    a2 = (const float*)d_in[ai+2];
    a3 = (const float*)d_in[ai+3];
    a4 = (const float*)d_in[ai+4];

    int A = (in_sizes[ai] + in_sizes[ai+1] + in_sizes[ai+2] + in_sizes[ai+3] + in_sizes[ai+4]) / 2;
    int B = in_sizes[1] / (M_GT * 3);
    int C = (int)((long long)in_sizes[0] / ((long long)B * A));

    float4* rec  = (float4*)d_ws;                                  // [B][5][128] = 80KB @ B=8
    size_t recBytes = (size_t)B * NLEV * M_GT * sizeof(float4);
    size_t off1 = (recBytes + 255) & ~(size_t)255;
    float2* parts = (float2*)((char*)d_ws + off1);                 // [B*GX]
    size_t partBytes = (size_t)B * GX * sizeof(float2);
    size_t off2 = (off1 + partBytes + 255) & ~(size_t)255;
    unsigned int* cnt = (unsigned int*)((char*)d_ws + off2);

    atss_summary_kernel<<<(B*M_GT)/4, 256, 0, stream>>>(ann, a0, a1, a2, a3, a4, rec, cnt);

    dim3 g2(GX, B);
    focal_kernel<<<g2, 256, 0, stream>>>(cls, rec, cid, a0, a1, a2, a3, a4,
                                         parts, cnt, (float*)d_out, A, C, B);
}

// Round 5
// 21.427 us; speedup vs baseline: 2.3270x; 2.3270x over previous
//
#include <hip/hip_runtime.h>
#include <math.h>

#define M_GT 128
#define NLEV 5
#define KCAND 135   // 5 levels * 27
#define TOPK_LOC 9
#define GX 186      // focal blocks per sample: 96+48+24+12+6 (256 anchors each, level-pure)

__device__ __forceinline__ float waveReduceSumF(float v) {
    #pragma unroll
    for (int off = 32; off > 0; off >>= 1)
        v += __shfl_xor(v, off, 64);
    return v;
}
// reduce within each 32-lane half-group (offsets stay inside the group)
__device__ __forceinline__ float group32ReduceSumF(float v) {
    #pragma unroll
    for (int off = 16; off > 0; off >>= 1)
        v += __shfl_xor(v, off, 64);
    return v;
}

// One wave per (b, m) pair; 4 pairs per 256-thread block.
// Writes per (b, level, m): float4 {gs, ge, thresh, window_lo(bitcast int)}.
__global__ __launch_bounds__(256) void atss_summary_kernel(
    const float* __restrict__ ann,   // [B, 128, 3]
    const float* __restrict__ a0,
    const float* __restrict__ a1,
    const float* __restrict__ a2,
    const float* __restrict__ a3,
    const float* __restrict__ a4,
    float4* __restrict__ rec)        // [B][NLEV][M_GT]
{
    const int Llev[NLEV] = {8192, 4096, 2048, 1024, 512};
    const float* aptr[NLEV] = {a0, a1, a2, a3, a4};

    int wid  = threadIdx.x >> 6;
    int lane = threadIdx.x & 63;
    int pair = blockIdx.x*4 + wid;
    int b = pair >> 7, m = pair & 127;
    const float* g = ann + ((size_t)b*M_GT + m)*3;
    float gs = g[0], ge = g[1];
    float gc = (gs + ge)*0.5f;
    float glen = ge - gs;

    // Per level: contiguous window of the 9 nearest locations.
    // Centers (j+0.5)*s are exact f32 (s = power of two); same-side distances
    // strictly ordered; cross-side tie -> lower index (matches lax.top_k).
    int lo_arr[NLEV];
    #pragma unroll
    for (int l = 0; l < NLEV; ++l) {
        int L = Llev[l];
        float s = 65536.0f / (float)L;
        int j0 = (int)floorf(gc / s);
        if (j0 < 0) j0 = 0;
        if (j0 > L-1) j0 = L-1;
        int best = j0;
        float bd = fabsf(((float)j0 + 0.5f)*s - gc);
        if (j0 > 0) {
            float d = fabsf(((float)j0 - 0.5f)*s - gc);
            if (d <= bd) { best = j0-1; bd = d; }
        }
        if (j0+1 < L) {
            float d = fabsf(((float)j0 + 1.5f)*s - gc);
            if (d < bd)  { best = j0+1; bd = d; }
        }
        int lo = best, hi = best+1;
        #pragma unroll
        for (int t = 1; t < TOPK_LOC; ++t) {
            float dl = (lo > 0) ? fabsf(((float)(lo-1) + 0.5f)*s - gc) : 3.4e38f;
            float dr = (hi < L) ? fabsf(((float)hi    + 0.5f)*s - gc) : 3.4e38f;
            if (dl <= dr) --lo; else ++hi;          // tie -> left (lower index)
        }
        lo_arr[l] = lo;
    }

    // 135 candidate IoUs spread over lanes -> mean + unbiased std -> thresh
    float iouv[3];
    int valid[3];
    float sum = 0.f;
    #pragma unroll
    for (int it = 0; it < 3; ++it) {
        int c = lane + it*64;
        valid[it] = 0; iouv[it] = 0.f;
        if (c < KCAND) {
            int lev = c / 27;
            int w   = c % 27;
            int loc = lo_arr[lev] + w/3;
            int sc  = w % 3;
            int lidx = loc*3 + sc;
            const float* ap = aptr[lev] + (size_t)lidx*2;
            float as_ = ap[0], ae_ = ap[1];
            float iw = fminf(ae_, ge) - fmaxf(as_, gs);
            iw = fmaxf(iw, 0.f);
            float ua = (ae_ - as_) + glen - iw;
            ua = fmaxf(ua, 1e-8f);
            float iou = iw / ua;
            iouv[it] = iou;
            valid[it] = 1;
            sum += iou;
        }
    }
    sum = waveReduceSumF(sum);
    float mean = sum / (float)KCAND;
    float s2 = 0.f;
    #pragma unroll
    for (int it = 0; it < 3; ++it)
        if (valid[it]) { float d = iouv[it] - mean; s2 += d*d; }
    s2 = waveReduceSumF(s2);
    float thresh = mean + sqrtf(s2 / (float)(KCAND - 1));  // ddof=1

    if (lane < NLEV) {
        int lo_sel = (lane == 0) ? lo_arr[0] :
                     (lane == 1) ? lo_arr[1] :
                     (lane == 2) ? lo_arr[2] :
                     (lane == 3) ? lo_arr[3] : lo_arr[4];
        rec[((size_t)b*NLEV + lane)*M_GT + m] =
            make_float4(gs, ge, thresh, __int_as_float(lo_sel));
    }
}

// One block = 256 consecutive anchors of one level. Early-issued global loads
// overlap the rec staging; ballot-built survivor mask (no LDS atomics);
// branchless focal channel loop. Writes one float2 partial per block.
__global__ __launch_bounds__(256) void focal_kernel(
    const float* __restrict__ cls,   // [B, A, C]
    const float4* __restrict__ rec,  // [B][NLEV][M_GT]
    const int* __restrict__ cidp,
    const float* __restrict__ a0,
    const float* __restrict__ a1,
    const float* __restrict__ a2,
    const float* __restrict__ a3,
    const float* __restrict__ a4,
    float2* __restrict__ parts,      // [B*GX] {sum, count}
    int A, int C)
{
    int xb = blockIdx.x;
    int b  = blockIdx.y;
    int lev, lstart;
    if      (xb <  96) { lev = 0; lstart = 0;   }
    else if (xb < 144) { lev = 1; lstart = 96;  }
    else if (xb < 168) { lev = 2; lstart = 144; }
    else if (xb < 180) { lev = 3; lstart = 168; }
    else               { lev = 4; lstart = 180; }
    const float* ap = (lev==0)?a0:(lev==1)?a1:(lev==2)?a2:(lev==3)?a3:a4;
    int gb = (lev==0)?0:(lev==1)?24576:(lev==2)?36864:(lev==3)?43008:46080;

    int a0l = (xb - lstart) * 256;   // level-local anchor offset
    int tid = threadIdx.x;
    int lidx = a0l + tid;
    int ga = gb + lidx;              // global anchor index

    // ---- issue all global loads up front (latency overlaps rec staging) ----
    const float2 aa = ((const float2*)ap)[lidx];
    const float* p = cls + ((size_t)b*A + ga)*C;
    float4 u, vv;
    bool c8 = (C == 8);
    if (c8) { u = ((const float4*)p)[0]; vv = ((const float4*)p)[1]; }
    int cid = *cidp;

    // ---- stage m-records, build overlap bitmask via ballot ----
    __shared__ float4 srec[M_GT];
    __shared__ unsigned long long smask[2];
    if (tid < M_GT) {
        float4 r = rec[((size_t)b*NLEV + lev)*M_GT + tid];
        srec[tid] = r;
        int lo = __float_as_int(r.w);
        int locLo = a0l / 3;
        int locHi = (a0l + 255) / 3;
        bool ov = (lo <= locHi) && (lo + (TOPK_LOC-1) >= locLo);
        unsigned long long mk = __ballot(ov);
        if ((tid & 63) == 0) smask[tid >> 6] = mk;
    }
    __syncthreads();

    // ---- positivity: iterate survivor m's (ascending, same order as ref) ----
    float as_ = aa.x, ae_ = aa.y;
    float cx  = (as_ + ae_) * 0.5f;
    int   loc = lidx / 3;
    int myp = 0;
    for (int w = 0; w < 2 && !myp; ++w) {
        unsigned long long mk = smask[w];
        while (mk && !myp) {
            int i = __ffsll((long long)mk) - 1;
            mk &= mk - 1;
            float4 r = srec[w*64 + i];
            int lo = __float_as_int(r.w);
            if ((unsigned)(loc - lo) < (unsigned)TOPK_LOC) {
                float gs = r.x, ge = r.y;
                float glen = ge - gs;
                float iw = fminf(ae_, ge) - fmaxf(as_, gs);
                iw = fmaxf(iw, 0.f);
                float ua = (ae_ - as_) + glen - iw;
                ua = fmaxf(ua, 1e-8f);
                float iou = iw / ua;
                if (iou >= r.z && fminf(cx - gs, ge - cx) > 0.01f) myp = 1;
            }
        }
    }

    // ---- focal sum over channels (branchless select per element) ----
    float local = 0.f;
    if (c8) {
        float x8[8] = {u.x, u.y, u.z, u.w, vv.x, vv.y, vv.z, vv.w};
        #pragma unroll
        for (int c = 0; c < 8; ++c) {
            float x = fminf(fmaxf(x8[c], 1e-4f), 0.9999f);
            float q = 1.f - x;
            float neg = 0.75f * x*x * (-__logf(q));
            float pst = 0.25f * q*q * (-__logf(x));
            local += ((myp != 0) && (c == cid)) ? pst : neg;
        }
    } else {
        for (int c = 0; c < C; ++c) {
            float x = fminf(fmaxf(p[c], 1e-4f), 0.9999f);
            float q = 1.f - x;
            float neg = 0.75f * x*x * (-__logf(q));
            float pst = 0.25f * q*q * (-__logf(x));
            local += ((myp != 0) && (c == cid)) ? pst : neg;
        }
    }

    // ---- block reduce -> one float2 partial ----
    local = waveReduceSumF(local);
    float cf = waveReduceSumF((float)myp);
    __shared__ float sred[4];
    __shared__ float cred[4];
    int wid = tid >> 6;
    if ((tid & 63) == 0) { sred[wid] = local; cred[wid] = cf; }
    __syncthreads();
    if (tid == 0) {
        float s = sred[0] + sred[1] + sred[2] + sred[3];
        float c = cred[0] + cred[1] + cred[2] + cred[3];
        parts[(size_t)b*GX + xb] = make_float2(s, c);
    }
}

// 256 threads: 32-lane group per sample (b = tid>>5, strided if B>8).
__global__ __launch_bounds__(256) void finalize_kernel(
    const float2* __restrict__ parts,
    float* __restrict__ out, int B)
{
    int tid = threadIdx.x;
    int grp = tid >> 5;
    int g0  = tid & 31;
    float tacc = 0.f;
    for (int b = grp; b < B; b += 8) {
        float s = 0.f, c = 0.f;
        for (int g = g0; g < GX; g += 32) {
            float2 pc = parts[(size_t)b*GX + g];
            s += pc.x; c += pc.y;
        }
        s = group32ReduceSumF(s);
        c = group32ReduceSumF(c);
        if (g0 == 0) tacc += s / fmaxf(c, 1.0f);
    }
    __shared__ float sh[8];
    if (g0 == 0) sh[grp] = tacc;
    __syncthreads();
    if (tid == 0) {
        float t = 0.f;
        #pragma unroll
        for (int i = 0; i < 8; ++i) t += sh[i];
        out[0] = t / (float)B;
    }
}

extern "C" void kernel_launch(void* const* d_in, const int* in_sizes, int n_in,
                              void* d_out, int out_size, void* d_ws, size_t ws_size,
                              hipStream_t stream)
{
    const float* cls = (const float*)d_in[0];
    const float* ann = (const float*)d_in[1];
    const int* cid;
    const float *a0, *a1, *a2, *a3, *a4;
    int ai;
    if (in_sizes[2] == 1) { cid = (const int*)d_in[2]; ai = 3; }
    else                  { cid = (const int*)d_in[7]; ai = 2; }
    a0 = (const float*)d_in[ai+0];
    a1 = (const float*)d_in[ai+1];
    a2 = (const float*)d_in[ai+2];
    a3 = (const float*)d_in[ai+3];
    a4 = (const float*)d_in[ai+4];

    int A = (in_sizes[ai] + in_sizes[ai+1] + in_sizes[ai+2] + in_sizes[ai+3] + in_sizes[ai+4]) / 2;
    int B = in_sizes[1] / (M_GT * 3);
    int C = (int)((long long)in_sizes[0] / ((long long)B * A));

    float4* rec  = (float4*)d_ws;                                  // [B][5][128] = 80KB @ B=8
    size_t recBytes = (size_t)B * NLEV * M_GT * sizeof(float4);
    size_t off1 = (recBytes + 255) & ~(size_t)255;
    float2* parts = (float2*)((char*)d_ws + off1);                 // [B*GX]

    atss_summary_kernel<<<(B*M_GT)/4, 256, 0, stream>>>(ann, a0, a1, a2, a3, a4, rec);

    dim3 g2(GX, B);
    focal_kernel<<<g2, 256, 0, stream>>>(cls, rec, cid, a0, a1, a2, a3, a4,
                                         parts, A, C);

    finalize_kernel<<<1, 256, 0, stream>>>(parts, (float*)d_out, B);
}